// Round 15
// baseline (984.182 us; speedup 1.0000x reference)
//
#include <hip/hip_runtime.h>

#define B_SZ 128
#define T_SZ 512
#define D_SZ 128
#define H_SZ 512

#define NG 8    // batch groups
#define GB 16   // batch rows per group
#define NS 4    // column slices
#define SN 128  // columns per slice

typedef _Float16 f16;
typedef _Float16 f16x8 __attribute__((ext_vector_type(8)));
typedef _Float16 f16x4 __attribute__((ext_vector_type(4)));
typedef float f32x4 __attribute__((ext_vector_type(4)));
typedef unsigned long long ull;
typedef unsigned int uint;

// lgkm-only barrier (LDS ordering, no vmcnt drain) for the reduction step.
#define BAR_LGKM()                                         \
  do {                                                     \
    asm volatile("s_waitcnt lgkmcnt(0)" ::: "memory");     \
    __builtin_amdgcn_sched_barrier(0);                     \
    __builtin_amdgcn_s_barrier();                          \
    __builtin_amdgcn_sched_barrier(0);                     \
  } while (0)

// ---------------- x_in = x @ W_in^T + b  (f16 MFMA, W in registers) --------
// Validated round 10/14: non-rec time 113 -> ~55 us, absmax unchanged.
__global__ __launch_bounds__(256) void input_proj_mfma(
    const float* __restrict__ x,     // [BT][128]
    const float* __restrict__ Win,   // [512][128] row-major
    const float* __restrict__ bias,  // [512]
    float* __restrict__ out)         // [BT][512]
{
  const int tid = threadIdx.x;
  const int w = tid >> 6;
  const int l = tid & 63;
  const int m = l & 15;
  const int kg = l >> 4;
  const int ht = w * 128;

  f16x8 af[8][4];
#pragma unroll
  for (int t = 0; t < 8; ++t) {
    const float* wr = Win + (size_t)(ht + t * 16 + m) * D_SZ;
#pragma unroll
    for (int kb = 0; kb < 4; ++kb) {
      const int k0 = kb * 32 + kg * 8;
      float4 u0 = *(const float4*)(wr + k0);
      float4 u1 = *(const float4*)(wr + k0 + 4);
      f16x8 a;
      a[0] = (f16)u0.x; a[1] = (f16)u0.y; a[2] = (f16)u0.z; a[3] = (f16)u0.w;
      a[4] = (f16)u1.x; a[5] = (f16)u1.y; a[6] = (f16)u1.z; a[7] = (f16)u1.w;
      af[t][kb] = a;
    }
  }

  for (int rt = 0; rt < 8; ++rt) {
    const size_t r0 = ((size_t)blockIdx.x * 8 + rt) * 16;
    const float* xr = x + (r0 + m) * D_SZ + kg * 8;
    f16x8 bf[4];
#pragma unroll
    for (int kb = 0; kb < 4; ++kb) {
      float4 u0 = *(const float4*)(xr + kb * 32);
      float4 u1 = *(const float4*)(xr + kb * 32 + 4);
      f16x8 a;
      a[0] = (f16)u0.x; a[1] = (f16)u0.y; a[2] = (f16)u0.z; a[3] = (f16)u0.w;
      a[4] = (f16)u1.x; a[5] = (f16)u1.y; a[6] = (f16)u1.z; a[7] = (f16)u1.w;
      bf[kb] = a;
    }
    f32x4 acc[8];
#pragma unroll
    for (int t = 0; t < 8; ++t) acc[t] = (f32x4){0.f, 0.f, 0.f, 0.f};
#pragma unroll
    for (int kb = 0; kb < 4; ++kb)
#pragma unroll
      for (int t = 0; t < 8; ++t)
        acc[t] = __builtin_amdgcn_mfma_f32_16x16x32_f16(af[t][kb], bf[kb], acc[t], 0, 0, 0);
#pragma unroll
    for (int t = 0; t < 8; ++t) {
      const int c0 = ht + t * 16 + kg * 4;
      float4 bb = *(const float4*)(bias + c0);
      float4 o;
      o.x = acc[t][0] + bb.x;
      o.y = acc[t][1] + bb.y;
      o.z = acc[t][2] + bb.z;
      o.w = acc[t][3] + bb.w;
      *(float4*)(out + (r0 + m) * H_SZ + c0) = o;
    }
  }
}

__device__ __forceinline__ float fast_tanh(float y) {
  float e = __expf(2.0f * y);
  return 1.0f - __fdividef(2.0f, e + 1.0f);
}

__device__ __forceinline__ ull ld_agent(const ull* p) {
  return __hip_atomic_load(p, __ATOMIC_RELAXED, __HIP_MEMORY_SCOPE_AGENT);
}

// ---------------- recurrence: round-8 exchange + 2-way K-split -------------
// 32 blocks x 512 threads. Wave w = (jg = w&3, kh = w>>2): computes j-tiles
// {2jg, 2jg+1} over 8 of 16 k-blocks (kh half); own-slice k-blocks are split
// 2/2 between halves so EVERY wave has 4 own-K MFMAs to cover the gather RTT.
// Per block/step: 64 B-frag ds_reads (was 128 — all 8 waves read identical
// frags; K-split halves the redundancy) + 8 reduction write/read pairs.
// Waves pair-exchange fp32 partials via 8KB LDS scratch (B_red, lgkm-only);
// each wave epilogues tile t_own = 2jg+kh. Exchange protocol/B1/B2 = round 8.
__global__ __launch_bounds__(512) void ltc_rec_mfma(
    float* __restrict__ seq,        // [B][T][H]  in: x_in, out: h_seq
    float* __restrict__ h_last,     // [B][H]
    const float* __restrict__ hin,  // [B][H]
    const float* __restrict__ tau,  // [B]
    const float* __restrict__ Wrec, // [H][H] row-major
    f16* __restrict__ ex)           // [2][NG][NS][GB][SN] exchange ring
{
  __shared__ f16 hs[2][GB * H_SZ];                       // 2x16KB, XOR-swizzled
  __shared__ __attribute__((aligned(16))) float red[8 * 64 * 4];  // 8KB

  const int tid = threadIdx.x;
  const int g = blockIdx.x & 7;
  const int slice = blockIdx.x >> 3;
  const int w = tid >> 6;          // wave 0..7
  const int jg = w & 3;            // j-tile pair group
  const int kh = w >> 2;           // k-half 0/1
  const int l = tid & 63;
  const int m = l & 15;            // batch-in-group (MFMA col)
  const int kg = l >> 4;           // 0..3
  const int t0 = 2 * jg;           // computed tiles t0, t0+1
  const int t_own = 2 * jg + kh;   // epilogue-owned tile
  const int j0 = slice * SN + t_own * 16 + kg * 4;
  const int b = g * GB + m;
  const int msk = (m & 7) << 3;

  // A-fragments: 2 tiles x 8 k-blocks (64 VGPR). k-block list per wave:
  // i=0,1 own-slice (slice*4+2kh+i); i=2..7 peer ((slice*4+4+6kh+(i-2))&15).
  f16x8 af0[8], af1[8];
  int ebase[8];
  {
    const float* wrA = Wrec + (size_t)(slice * SN + t0 * 16 + m) * H_SZ;
    const float* wrB = wrA + 16 * H_SZ;
#pragma unroll
    for (int i = 0; i < 8; ++i) {
      const int f = (i < 2 ? (slice * 4 + 2 * kh + i)
                           : (slice * 4 + 4 + 6 * kh + (i - 2))) & 15;
      const int k0 = f * 32 + kg * 8;
      float4 u0 = *(const float4*)(wrA + k0);
      float4 u1 = *(const float4*)(wrA + k0 + 4);
      f16x8 a;
      a[0] = (f16)u0.x; a[1] = (f16)u0.y; a[2] = (f16)u0.z; a[3] = (f16)u0.w;
      a[4] = (f16)u1.x; a[5] = (f16)u1.y; a[6] = (f16)u1.z; a[7] = (f16)u1.w;
      af0[i] = a;
      float4 v0 = *(const float4*)(wrB + k0);
      float4 v1 = *(const float4*)(wrB + k0 + 4);
      f16x8 c;
      c[0] = (f16)v0.x; c[1] = (f16)v0.y; c[2] = (f16)v0.z; c[3] = (f16)v0.w;
      c[4] = (f16)v1.x; c[5] = (f16)v1.y; c[6] = (f16)v1.z; c[7] = (f16)v1.w;
      af1[i] = c;
      ebase[i] = (m * H_SZ + f * 32 + kg * 8) ^ msk;
    }
  }

  float hreg[4];
  {
    float4 h0 = *(const float4*)(hin + (size_t)b * H_SZ + j0);
    hreg[0] = h0.x; hreg[1] = h0.y; hreg[2] = h0.z; hreg[3] = h0.w;
  }
  const float itau = 1.0f / tau[b];

  // init: full h_0 into hs[0] as f16
  {
    const int mr = tid >> 5;
    const int c4 = (tid & 31) * 4;
#pragma unroll
    for (int p = 0; p < 4; ++p) {
      const int col = p * SN + c4;
      float4 v = *(const float4*)(hin + (size_t)(g * GB + mr) * H_SZ + col);
      const int e = (mr * H_SZ + col) ^ ((mr & 7) << 3);
      f16x4 hf;
      hf[0] = (f16)v.x; hf[1] = (f16)v.y; hf[2] = (f16)v.z; hf[3] = (f16)v.w;
      *(f16x4*)&hs[0][e] = hf;
    }
  }
  __syncthreads();

  // exchange addressing (round-8 verbatim; publish col uses t_own)
  const size_t EXB = (size_t)GB * SN;                 // 2048 f16
  const size_t RING_ULL = (size_t)NG * NS * EXB / 4;  // 16384 ull per slot
  ull* pub0 = (ull*)(ex + ((size_t)g * NS + slice) * EXB + (size_t)m * SN + (t_own * 16 + kg * 4));

  const int gmr = tid >> 5;
  const int gc4 = (tid & 31) * 4;
  const int psa = (slice + 1) & 3, psb = (slice + 2) & 3, psc = (slice + 3) & 3;
  const ull* ga0 = (const ull*)(ex + ((size_t)g * NS + psa) * EXB + (size_t)gmr * SN + gc4);
  const ull* gb0 = (const ull*)(ex + ((size_t)g * NS + psb) * EXB + (size_t)gmr * SN + gc4);
  const ull* gc0 = (const ull*)(ex + ((size_t)g * NS + psc) * EXB + (size_t)gmr * SN + gc4);
  const int ea = (gmr * H_SZ + psa * SN + gc4) ^ ((gmr & 7) << 3);
  const int eb = (gmr * H_SZ + psb * SN + gc4) ^ ((gmr & 7) << 3);
  const int ec = (gmr * H_SZ + psc * SN + gc4) ^ ((gmr & 7) << 3);
  const int eown = (m * H_SZ + j0) ^ msk;

  // reduction scratch slots (write own, read pair's)
  float* redw = red + ((size_t)(jg * 2 + kh) * 64 + l) * 4;
  const float* redr = red + ((size_t)(jg * 2 + (1 - kh)) * 64 + l) * 4;

  float* seqp = seq + (size_t)b * T_SZ * H_SZ + j0;
  float4 xin = *(const float4*)seqp;  // step-0 x_in prefetch

  for (int s = 0; s < T_SZ; ++s) {
    const int cur = s & 1, nxt = cur ^ 1;

    // ---- issue gather loads for h_s peer slices (pub'd end of iter s-1) ----
    ull w0 = 0, w1 = 0, w2 = 0;
    const size_t proff = nxt ? RING_ULL : 0;          // slot (s-1)&1
    const ull ptag = (ull)(((s - 1) >> 1) & 1);
    if (s > 0) {
      w0 = ld_agent(ga0 + proff);
      w1 = ld_agent(gb0 + proff);
      w2 = ld_agent(gc0 + proff);
    }

    // ---- own-K MFMA (i=0,1; own-slice k, no peer dep): covers gather RTT ----
    f32x4 acc0 = {0.f, 0.f, 0.f, 0.f};
    f32x4 acc1 = {0.f, 0.f, 0.f, 0.f};
    {
      f16x8 bf = *(const f16x8*)&hs[cur][ebase[0]];
      acc0 = __builtin_amdgcn_mfma_f32_16x16x32_f16(af0[0], bf, acc0, 0, 0, 0);
      acc1 = __builtin_amdgcn_mfma_f32_16x16x32_f16(af1[0], bf, acc1, 0, 0, 0);
      bf = *(const f16x8*)&hs[cur][ebase[1]];
      acc0 = __builtin_amdgcn_mfma_f32_16x16x32_f16(af0[1], bf, acc0, 0, 0, 0);
      acc1 = __builtin_amdgcn_mfma_f32_16x16x32_f16(af1[1], bf, acc1, 0, 0, 0);
    }

    if (s > 0) {
      // ---- poll tags; reload only stale words ----
      while ((w0 & 1ULL) != ptag) w0 = ld_agent(ga0 + proff);
      while ((w1 & 1ULL) != ptag) w1 = ld_agent(gb0 + proff);
      while ((w2 & 1ULL) != ptag) w2 = ld_agent(gc0 + proff);
      // ---- peer slices of h_s into hs[cur] peer cols ----
      *(f16x4*)&hs[cur][ea] = __builtin_bit_cast(f16x4, w0);
      *(f16x4*)&hs[cur][eb] = __builtin_bit_cast(f16x4, w1);
      *(f16x4*)&hs[cur][ec] = __builtin_bit_cast(f16x4, w2);
      __syncthreads();  // B1: peer cols visible block-wide (pacing kept)
    }

    // ---- peer-K MFMA (i=2..7, 2 independent chains via acc0/acc1) ----
    {
      f16x8 bf = *(const f16x8*)&hs[cur][ebase[2]];
      acc0 = __builtin_amdgcn_mfma_f32_16x16x32_f16(af0[2], bf, acc0, 0, 0, 0);
      acc1 = __builtin_amdgcn_mfma_f32_16x16x32_f16(af1[2], bf, acc1, 0, 0, 0);
      bf = *(const f16x8*)&hs[cur][ebase[3]];
      acc0 = __builtin_amdgcn_mfma_f32_16x16x32_f16(af0[3], bf, acc0, 0, 0, 0);
      acc1 = __builtin_amdgcn_mfma_f32_16x16x32_f16(af1[3], bf, acc1, 0, 0, 0);
      bf = *(const f16x8*)&hs[cur][ebase[4]];
      acc0 = __builtin_amdgcn_mfma_f32_16x16x32_f16(af0[4], bf, acc0, 0, 0, 0);
      acc1 = __builtin_amdgcn_mfma_f32_16x16x32_f16(af1[4], bf, acc1, 0, 0, 0);
      bf = *(const f16x8*)&hs[cur][ebase[5]];
      acc0 = __builtin_amdgcn_mfma_f32_16x16x32_f16(af0[5], bf, acc0, 0, 0, 0);
      acc1 = __builtin_amdgcn_mfma_f32_16x16x32_f16(af1[5], bf, acc1, 0, 0, 0);
      bf = *(const f16x8*)&hs[cur][ebase[6]];
      acc0 = __builtin_amdgcn_mfma_f32_16x16x32_f16(af0[6], bf, acc0, 0, 0, 0);
      acc1 = __builtin_amdgcn_mfma_f32_16x16x32_f16(af1[6], bf, acc1, 0, 0, 0);
      bf = *(const f16x8*)&hs[cur][ebase[7]];
      acc0 = __builtin_amdgcn_mfma_f32_16x16x32_f16(af0[7], bf, acc0, 0, 0, 0);
      acc1 = __builtin_amdgcn_mfma_f32_16x16x32_f16(af1[7], bf, acc1, 0, 0, 0);
    }

    // ---- cross-wave partial reduction (pairs (jg,0)<->(jg,1)) ----
    f32x4 accOwnP, accOth;
    if (kh == 0) { accOwnP = acc0; accOth = acc1; }  // own tile t0, other t0+1
    else         { accOwnP = acc1; accOth = acc0; }  // own tile t0+1, other t0
    *(f32x4*)redw = accOth;
    BAR_LGKM();  // B_red: LDS-only ordering (nothing in vm queue needs drain)
    f32x4 acc = accOwnP + *(const f32x4*)redr;

    // ---- epilogue (tile t_own) ----
    float4 hv;
    hv.x = fmaf(fast_tanh(xin.x + acc[0]) - hreg[0], itau, hreg[0]);
    hv.y = fmaf(fast_tanh(xin.y + acc[1]) - hreg[1], itau, hreg[1]);
    hv.z = fmaf(fast_tanh(xin.z + acc[2]) - hreg[2], itau, hreg[2]);
    hv.w = fmaf(fast_tanh(xin.w + acc[3]) - hreg[3], itau, hreg[3]);
    hreg[0] = hv.x; hreg[1] = hv.y; hreg[2] = hv.z; hreg[3] = hv.w;

    f16x4 hf;
    hf[0] = (f16)hv.x; hf[1] = (f16)hv.y; hf[2] = (f16)hv.z; hf[3] = (f16)hv.w;

    // ---- publish h_{s+1}: slot s&1, tag (s>>1)&1 ----
    {
      ull bits = __builtin_bit_cast(ull, hf);
      bits = (bits & ~1ULL) | (ull)((s >> 1) & 1);
      __hip_atomic_store(pub0 + (cur ? RING_ULL : 0), bits,
                         __ATOMIC_RELAXED, __HIP_MEMORY_SCOPE_AGENT);
    }

    // ---- local tail ----
    *(f16x4*)&hs[nxt][eown] = hf;       // own cols of h_{s+1} (exact f16)
    *(float4*)seqp = hv;                // h_seq output (plain cached)
    seqp += H_SZ;
    xin = *(const float4*)seqp;         // x_in prefetch for s+1

    __syncthreads();  // B2: own cols ready + vmcnt drain (peer pacing)
  }

  float4 hv;
  hv.x = hreg[0]; hv.y = hreg[1]; hv.z = hreg[2]; hv.w = hreg[3];
  *(float4*)(h_last + (size_t)b * H_SZ + j0) = hv;
}

extern "C" void kernel_launch(void* const* d_in, const int* in_sizes, int n_in,
                              void* d_out, int out_size, void* d_ws, size_t ws_size,
                              hipStream_t stream) {
  const float* x     = (const float*)d_in[0];
  const float* hin   = (const float*)d_in[1];
  const float* tau   = (const float*)d_in[2];
  const float* Win_w = (const float*)d_in[3];
  const float* Win_b = (const float*)d_in[4];
  const float* Wrec  = (const float*)d_in[5];

  float* out    = (float*)d_out;
  float* seq    = out;
  float* h_last = out + (size_t)B_SZ * T_SZ * H_SZ;

  f16* ex = (f16*)d_ws;  // 256 KB (2-slot ring)

  // ring to 0xFF: LSB=1 never matches the first (tag-0) poll of each slot.
  hipMemsetAsync(ex, 0xFF, 2 * NG * NS * GB * SN * sizeof(f16), stream);

  input_proj_mfma<<<512, 256, 0, stream>>>(x, Win_w, Win_b, seq);
  ltc_rec_mfma<<<NG * NS, 512, 0, stream>>>(seq, h_last, hin, tau, Wrec, ex);
}

// Round 16
// 977.986 us; speedup vs baseline: 1.0063x; 1.0063x over previous
//
#include <hip/hip_runtime.h>

#define B_SZ 128
#define T_SZ 512
#define D_SZ 128
#define H_SZ 512

#define NG 8    // batch groups
#define GB 16   // batch rows per group
#define NS 4    // column slices
#define SN 128  // columns per slice
#define RING_ULL_TOTAL 65536  // 2 slots * NG*NS*GB*SN f16 / 4 = 512 KB

typedef _Float16 f16;
typedef _Float16 f16x8 __attribute__((ext_vector_type(8)));
typedef _Float16 f16x4 __attribute__((ext_vector_type(4)));
typedef float f32x4 __attribute__((ext_vector_type(4)));
typedef unsigned long long ull;
typedef unsigned int uint;

// ---------------- x_in = x @ W_in^T + b  (f16 MFMA, W in registers) --------
// Also initializes the exchange ring to 0xFF (tag LSB=1 never false-matches
// the rec kernel's first tag-0 polls; defeats the harness's 0xAA poison).
// Kernel-boundary L2 writeback makes these stores visible to sc1 loads.
__global__ __launch_bounds__(256) void input_proj_mfma(
    const float* __restrict__ x,     // [BT][128]
    const float* __restrict__ Win,   // [512][128] row-major
    const float* __restrict__ bias,  // [512]
    float* __restrict__ out,         // [BT][512]
    ull* __restrict__ ring)          // [RING_ULL_TOTAL]
{
  const int tid = threadIdx.x;

  // ring init: blocks 0..255, one coalesced 8B store per thread
  {
    const uint gid = blockIdx.x * 256u + (uint)tid;
    if (gid < (uint)RING_ULL_TOTAL) ring[gid] = ~0ULL;
  }

  const int w = tid >> 6;
  const int l = tid & 63;
  const int m = l & 15;
  const int kg = l >> 4;
  const int ht = w * 128;

  f16x8 af[8][4];
#pragma unroll
  for (int t = 0; t < 8; ++t) {
    const float* wr = Win + (size_t)(ht + t * 16 + m) * D_SZ;
#pragma unroll
    for (int kb = 0; kb < 4; ++kb) {
      const int k0 = kb * 32 + kg * 8;
      float4 u0 = *(const float4*)(wr + k0);
      float4 u1 = *(const float4*)(wr + k0 + 4);
      f16x8 a;
      a[0] = (f16)u0.x; a[1] = (f16)u0.y; a[2] = (f16)u0.z; a[3] = (f16)u0.w;
      a[4] = (f16)u1.x; a[5] = (f16)u1.y; a[6] = (f16)u1.z; a[7] = (f16)u1.w;
      af[t][kb] = a;
    }
  }

  for (int rt = 0; rt < 8; ++rt) {
    const size_t r0 = ((size_t)blockIdx.x * 8 + rt) * 16;
    const float* xr = x + (r0 + m) * D_SZ + kg * 8;
    f16x8 bf[4];
#pragma unroll
    for (int kb = 0; kb < 4; ++kb) {
      float4 u0 = *(const float4*)(xr + kb * 32);
      float4 u1 = *(const float4*)(xr + kb * 32 + 4);
      f16x8 a;
      a[0] = (f16)u0.x; a[1] = (f16)u0.y; a[2] = (f16)u0.z; a[3] = (f16)u0.w;
      a[4] = (f16)u1.x; a[5] = (f16)u1.y; a[6] = (f16)u1.z; a[7] = (f16)u1.w;
      bf[kb] = a;
    }
    f32x4 acc[8];
#pragma unroll
    for (int t = 0; t < 8; ++t) acc[t] = (f32x4){0.f, 0.f, 0.f, 0.f};
#pragma unroll
    for (int kb = 0; kb < 4; ++kb)
#pragma unroll
      for (int t = 0; t < 8; ++t)
        acc[t] = __builtin_amdgcn_mfma_f32_16x16x32_f16(af[t][kb], bf[kb], acc[t], 0, 0, 0);
#pragma unroll
    for (int t = 0; t < 8; ++t) {
      const int c0 = ht + t * 16 + kg * 4;
      float4 bb = *(const float4*)(bias + c0);
      float4 o;
      o.x = acc[t][0] + bb.x;
      o.y = acc[t][1] + bb.y;
      o.z = acc[t][2] + bb.z;
      o.w = acc[t][3] + bb.w;
      *(float4*)(out + (r0 + m) * H_SZ + c0) = o;
    }
  }
}

__device__ __forceinline__ float fast_tanh(float y) {
  float e = __expf(2.0f * y);
  return 1.0f - __fdividef(2.0f, e + 1.0f);
}

__device__ __forceinline__ ull ld_agent(const ull* p) {
  return __hip_atomic_load(p, __ATOMIC_RELAXED, __HIP_MEMORY_SCOPE_AGENT);
}

// ---------------- recurrence: ROUND-8/14 VERBATIM (rec ~917 us, VGPR 84) ---
// 32 blocks x 512 threads (8 waves). Exchange via SELF-TAGGED 8B payloads
// (LSB of f16[0] = generation parity) on a depth-2 LLC ring (relaxed sc1).
// Per iter: issue gathers -> own-K MFMA (covers LLC RTT) -> poll tags ->
// peer cols into hs[cur] -> B1 -> peer-K MFMA -> epilogue -> tagged publish
// -> own cols into hs[nxt] -> B2 (__syncthreads).
// B2's vmcnt(0) drain is LOAD-BEARING twice over: (a) paces the 4 peer
// blocks so top-of-iter gathers hit first try (round 13: lgkm-only = +88us);
// (b) orders same-slot generational publishes across graph replays
// (same-address coherence holds per slot only because the prior publish is
// ACKED before the next iteration begins).
// Structural floor evidence: K-split (r15) halved LDS reads+conflicts with
// zero gain -> compute/LDS fully hidden; step cost = exchange RTT + drain.
__global__ __launch_bounds__(512) void ltc_rec_mfma(
    float* __restrict__ seq,        // [B][T][H]  in: x_in, out: h_seq
    float* __restrict__ h_last,     // [B][H]
    const float* __restrict__ hin,  // [B][H]
    const float* __restrict__ tau,  // [B]
    const float* __restrict__ Wrec, // [H][H] row-major
    f16* __restrict__ ex)           // [2][NG][NS][GB][SN] exchange ring
{
  __shared__ f16 hs[2][GB * H_SZ];  // double-buffered, XOR-swizzled, 2x16KB

  const int tid = threadIdx.x;
  const int g = blockIdx.x & 7;
  const int slice = blockIdx.x >> 3;
  const int w = tid >> 6;          // wave 0..7
  const int l = tid & 63;
  const int m = l & 15;            // batch-in-group (MFMA col)
  const int kg = l >> 4;           // 0..3
  const int jt = slice * SN + w * 16;
  const int j0 = jt + kg * 4;
  const int b = g * GB + m;

  // one-time: A-fragments, pre-rotated so in-loop indices are literals
  // (rule 20: runtime-indexed ext_vector arrays spill to scratch — r7).
  f16x8 afrag[16];
  {
    const float* wr = Wrec + (size_t)(jt + m) * H_SZ;
#pragma unroll
    for (int ff = 0; ff < 16; ++ff) {
      const int f = (slice * 4 + ff) & 15;   // runtime k-block, load-addr only
      const int k0 = f * 32 + kg * 8;
      float4 u0 = *(const float4*)(wr + k0);
      float4 u1 = *(const float4*)(wr + k0 + 4);
      f16x8 a;
      a[0] = (f16)u0.x; a[1] = (f16)u0.y; a[2] = (f16)u0.z; a[3] = (f16)u0.w;
      a[4] = (f16)u1.x; a[5] = (f16)u1.y; a[6] = (f16)u1.z; a[7] = (f16)u1.w;
      afrag[ff] = a;                          // compile-time index
    }
  }

  float hreg[4];
  {
    float4 h0 = *(const float4*)(hin + (size_t)b * H_SZ + j0);
    hreg[0] = h0.x; hreg[1] = h0.y; hreg[2] = h0.z; hreg[3] = h0.w;
  }
  const float itau = 1.0f / tau[b];

  // init: full h_0 into hs[0] as f16
  {
    const int mr = tid >> 5;         // 0..15
    const int c4 = (tid & 31) * 4;
#pragma unroll
    for (int p = 0; p < 4; ++p) {
      const int col = p * SN + c4;
      float4 v = *(const float4*)(hin + (size_t)(g * GB + mr) * H_SZ + col);
      const int e = (mr * H_SZ + col) ^ ((mr & 7) << 3);
      f16x4 hf;
      hf[0] = (f16)v.x; hf[1] = (f16)v.y; hf[2] = (f16)v.z; hf[3] = (f16)v.w;
      *(f16x4*)&hs[0][e] = hf;
    }
  }
  __syncthreads();

  // exchange addressing (ull units)
  const size_t EXB = (size_t)GB * SN;                 // 2048 f16
  const size_t RING_ULL = (size_t)NG * NS * EXB / 4;  // 16384 ull per slot
  ull* pub0 = (ull*)(ex + ((size_t)g * NS + slice) * EXB + (size_t)m * SN + (w * 16 + kg * 4));

  const int gmr = tid >> 5;
  const int gc4 = (tid & 31) * 4;
  const int psa = (slice + 1) & 3, psb = (slice + 2) & 3, psc = (slice + 3) & 3;
  const ull* ga0 = (const ull*)(ex + ((size_t)g * NS + psa) * EXB + (size_t)gmr * SN + gc4);
  const ull* gb0 = (const ull*)(ex + ((size_t)g * NS + psb) * EXB + (size_t)gmr * SN + gc4);
  const ull* gc0 = (const ull*)(ex + ((size_t)g * NS + psc) * EXB + (size_t)gmr * SN + gc4);
  const int ea = (gmr * H_SZ + psa * SN + gc4) ^ ((gmr & 7) << 3);
  const int eb = (gmr * H_SZ + psb * SN + gc4) ^ ((gmr & 7) << 3);
  const int ec = (gmr * H_SZ + psc * SN + gc4) ^ ((gmr & 7) << 3);
  const int eown = (m * H_SZ + j0) ^ ((m & 7) << 3);

  // base byte-offsets for the k-block LDS reads (runtime f folded into
  // address arithmetic; array indices below stay literal)
  int ebase[16];
#pragma unroll
  for (int ff = 0; ff < 16; ++ff) {
    const int f = (slice * 4 + ff) & 15;
    ebase[ff] = (m * H_SZ + f * 32 + kg * 8) ^ ((m & 7) << 3);
  }

  float* seqp = seq + (size_t)b * T_SZ * H_SZ + j0;
  float4 xin = *(const float4*)seqp;  // step-0 x_in prefetch

  for (int s = 0; s < T_SZ; ++s) {
    const int cur = s & 1, nxt = cur ^ 1;

    // ---- issue gather loads for h_s peer slices (pub'd end of iter s-1) ----
    ull w0 = 0, w1 = 0, w2 = 0;
    const size_t proff = nxt ? RING_ULL : 0;          // slot (s-1)&1
    const ull ptag = (ull)(((s - 1) >> 1) & 1);
    if (s > 0) {
      w0 = ld_agent(ga0 + proff);
      w1 = ld_agent(gb0 + proff);
      w2 = ld_agent(gc0 + proff);
    }

    // ---- own-K MFMA (afrag[0..3], no peer dep): covers the gather RTT ----
    f32x4 accA = {0.f, 0.f, 0.f, 0.f};
    accA = __builtin_amdgcn_mfma_f32_16x16x32_f16(afrag[0], *(const f16x8*)&hs[cur][ebase[0]], accA, 0, 0, 0);
    accA = __builtin_amdgcn_mfma_f32_16x16x32_f16(afrag[1], *(const f16x8*)&hs[cur][ebase[1]], accA, 0, 0, 0);
    accA = __builtin_amdgcn_mfma_f32_16x16x32_f16(afrag[2], *(const f16x8*)&hs[cur][ebase[2]], accA, 0, 0, 0);
    accA = __builtin_amdgcn_mfma_f32_16x16x32_f16(afrag[3], *(const f16x8*)&hs[cur][ebase[3]], accA, 0, 0, 0);

    if (s > 0) {
      // ---- poll tags; reload only stale words ----
      while ((w0 & 1ULL) != ptag) w0 = ld_agent(ga0 + proff);
      while ((w1 & 1ULL) != ptag) w1 = ld_agent(gb0 + proff);
      while ((w2 & 1ULL) != ptag) w2 = ld_agent(gc0 + proff);
      // ---- peer slices of h_s into hs[cur] peer cols ----
      *(f16x4*)&hs[cur][ea] = __builtin_bit_cast(f16x4, w0);
      *(f16x4*)&hs[cur][eb] = __builtin_bit_cast(f16x4, w1);
      *(f16x4*)&hs[cur][ec] = __builtin_bit_cast(f16x4, w2);
      __syncthreads();  // B1: peer cols visible block-wide
    }

    // ---- peer-K MFMA (afrag[4..15], 2 chains) ----
    f32x4 accB = {0.f, 0.f, 0.f, 0.f};
    f32x4 accC = {0.f, 0.f, 0.f, 0.f};
    accB = __builtin_amdgcn_mfma_f32_16x16x32_f16(afrag[4],  *(const f16x8*)&hs[cur][ebase[4]],  accB, 0, 0, 0);
    accB = __builtin_amdgcn_mfma_f32_16x16x32_f16(afrag[5],  *(const f16x8*)&hs[cur][ebase[5]],  accB, 0, 0, 0);
    accB = __builtin_amdgcn_mfma_f32_16x16x32_f16(afrag[6],  *(const f16x8*)&hs[cur][ebase[6]],  accB, 0, 0, 0);
    accB = __builtin_amdgcn_mfma_f32_16x16x32_f16(afrag[7],  *(const f16x8*)&hs[cur][ebase[7]],  accB, 0, 0, 0);
    accB = __builtin_amdgcn_mfma_f32_16x16x32_f16(afrag[8],  *(const f16x8*)&hs[cur][ebase[8]],  accB, 0, 0, 0);
    accB = __builtin_amdgcn_mfma_f32_16x16x32_f16(afrag[9],  *(const f16x8*)&hs[cur][ebase[9]],  accB, 0, 0, 0);
    accC = __builtin_amdgcn_mfma_f32_16x16x32_f16(afrag[10], *(const f16x8*)&hs[cur][ebase[10]], accC, 0, 0, 0);
    accC = __builtin_amdgcn_mfma_f32_16x16x32_f16(afrag[11], *(const f16x8*)&hs[cur][ebase[11]], accC, 0, 0, 0);
    accC = __builtin_amdgcn_mfma_f32_16x16x32_f16(afrag[12], *(const f16x8*)&hs[cur][ebase[12]], accC, 0, 0, 0);
    accC = __builtin_amdgcn_mfma_f32_16x16x32_f16(afrag[13], *(const f16x8*)&hs[cur][ebase[13]], accC, 0, 0, 0);
    accC = __builtin_amdgcn_mfma_f32_16x16x32_f16(afrag[14], *(const f16x8*)&hs[cur][ebase[14]], accC, 0, 0, 0);
    accC = __builtin_amdgcn_mfma_f32_16x16x32_f16(afrag[15], *(const f16x8*)&hs[cur][ebase[15]], accC, 0, 0, 0);
    f32x4 acc = accA + accB + accC;

    // ---- epilogue ----
    float4 hv;
    hv.x = fmaf(fast_tanh(xin.x + acc[0]) - hreg[0], itau, hreg[0]);
    hv.y = fmaf(fast_tanh(xin.y + acc[1]) - hreg[1], itau, hreg[1]);
    hv.z = fmaf(fast_tanh(xin.z + acc[2]) - hreg[2], itau, hreg[2]);
    hv.w = fmaf(fast_tanh(xin.w + acc[3]) - hreg[3], itau, hreg[3]);
    hreg[0] = hv.x; hreg[1] = hv.y; hreg[2] = hv.z; hreg[3] = hv.w;

    f16x4 hf;
    hf[0] = (f16)hv.x; hf[1] = (f16)hv.y; hf[2] = (f16)hv.z; hf[3] = (f16)hv.w;

    // ---- publish h_{s+1} FIRST: tagged word, slot s&1, tag (s>>1)&1 ----
    {
      ull bits = __builtin_bit_cast(ull, hf);
      bits = (bits & ~1ULL) | (ull)((s >> 1) & 1);
      __hip_atomic_store(pub0 + (cur ? RING_ULL : 0), bits,
                         __ATOMIC_RELAXED, __HIP_MEMORY_SCOPE_AGENT);
    }

    // ---- local tail ----
    *(f16x4*)&hs[nxt][eown] = hf;       // own slice of h_{s+1} (exact f16)
    *(float4*)seqp = hv;                // h_seq output (plain cached)
    seqp += H_SZ;
    xin = *(const float4*)seqp;         // x_in prefetch for s+1

    __syncthreads();  // B2: own cols ready + vmcnt drain (pacing + slot order)
  }

  float4 hv;
  hv.x = hreg[0]; hv.y = hreg[1]; hv.z = hreg[2]; hv.w = hreg[3];
  *(float4*)(h_last + (size_t)b * H_SZ + j0) = hv;
}

extern "C" void kernel_launch(void* const* d_in, const int* in_sizes, int n_in,
                              void* d_out, int out_size, void* d_ws, size_t ws_size,
                              hipStream_t stream) {
  const float* x     = (const float*)d_in[0];
  const float* hin   = (const float*)d_in[1];
  const float* tau   = (const float*)d_in[2];
  const float* Win_w = (const float*)d_in[3];
  const float* Win_b = (const float*)d_in[4];
  const float* Wrec  = (const float*)d_in[5];

  float* out    = (float*)d_out;
  float* seq    = out;
  float* h_last = out + (size_t)B_SZ * T_SZ * H_SZ;

  f16* ex = (f16*)d_ws;  // 512 KB (2-slot ring), init'd inside input_proj_mfma

  input_proj_mfma<<<512, 256, 0, stream>>>(x, Win_w, Win_b, seq, (ull*)ex);
  ltc_rec_mfma<<<NG * NS, 512, 0, stream>>>(seq, h_last, hin, tau, Wrec, ex);
}